// Round 9
// baseline (262.238 us; speedup 1.0000x reference)
//
#include <hip/hip_runtime.h>
#include <math.h>

#define N_NODES 100000
#define D_FEAT  256
#define TOP_K   50000
#define NBINS   16384       // central bucket ~10 elems (sigmoid(N(0,1)) density)
#define NCHUNK  16          // NBINS / 1024 chunks for the parallel scan
#define CUTPOS  (N_NODES - TOP_K)
#define ROWSTRIDE 260       // 256 + 4 pad: bank = (4g + l + 8i) % 32 -> 2-way = free
#define NBITW   3200        // member bitmask words (ceil(100000/32)=3125, padded)
#define FUSE_GRID   2048    // emit||edge fused kernel (8 blocks/CU co-resident)
#define EMIT_BLOCKS 1408    // split ~ NT-write-dominated emit vs L3-read edge

// clang native vectors: __builtin_nontemporal_store requires these (not the
// HIP_vector_type structs float4/float2).
typedef float  fx4 __attribute__((ext_vector_type(4)));
typedef float  fx2 __attribute__((ext_vector_type(2)));

// Sort key: (float bits of s << 32) | ~id.  s = sigmoid >= 0, so IEEE bit
// order == numeric order; ascending u64 == (s asc, id desc) — reversed read
// gives (s desc, id asc) = lax.top_k tie rule.  One cacheline per element in
// the random scatter (vs two for separate ss/si), one dependent load in emit.
//
// Workspace layout (byte offsets, all 8/16B-aligned):
//         0 : s32      float[N_NODES]   (400,000)
//   400,000 : sk       u64[N_NODES]     (800,000)  bucket-sorted keys
// 1,200,000 : hist     int[NBINS]       ( 65,536)  } contiguous zero region
// 1,265,536 : bits     uint[NBITW]      ( 12,800)  } (78,336 B memset)
// 1,278,336 : offs     int[NBINS]       ( 65,536)  chunk-LOCAL exclusive offsets
// 1,343,872 : cursor   int[NBINS]       ( 65,536)
// 1,409,408 : chunkSum int[NCHUNK]      (     64)

__device__ __forceinline__ int bucket_of(float s) {
    int b = (int)(s * 16384.0f);
    return min(max(b, 0), NBINS - 1);
}

// numpy SIMD float32 exp (FMA universal-intrinsics path) — bit-exact, verified R6.
__device__ __forceinline__ float np_expf(float x) {
    float q  = rintf(x * 1.44269504088896341f);
    float xr = fmaf(-q, 0.693359375f, x);
    xr       = fmaf(-q, -2.12194440e-4f, xr);
    float x2 = xr * xr;
    float p  = 1.9875691500E-4f;
    p = fmaf(p, xr, 1.3981999507E-3f);
    p = fmaf(p, xr, 8.3334519073E-3f);
    p = fmaf(p, xr, 4.1665795894E-2f);
    p = fmaf(p, xr, 1.6666665459E-1f);
    p = fmaf(p, xr, 5.0000001201E-1f);
    p = fmaf(p, x2, xr);
    p = p + 1.0f;
    return ldexpf(p, (int)q);
}

// OpenBLAS sgemv_t emulation, parallelized 8 lanes/node (bit-exact numerics):
// lane 8g+l runs chain l (k = i*8+l, i=0..31, serial fmaf) for node g of its wave;
// merge via shfl_xor 1,2,4 reproduces ((a0+a1)+(a2+a3))+((a4+a5)+(a6+a7)).
// Block = 256 thr = 4 waves = 32 nodes; rows staged to LDS coalesced.
// DO NOT TOUCH the numerics: bit-exact scores gate the top-k tie boundary.
__global__ void score_kernel(const float* __restrict__ h,
                             const float* __restrict__ W,
                             const float* __restrict__ bvec,
                             float* __restrict__ s32,
                             int* __restrict__ hist) {
    __shared__ float rows[32 * ROWSTRIDE];   // 33,280 B
    __shared__ float wl[256];
    int tid  = threadIdx.x;
    int wave = tid >> 6;
    int lane = tid & 63;
    int g    = lane >> 3;    // node within wave's 8
    int l    = lane & 7;     // chain id

    wl[tid] = W[tid];

    // stage this wave's 8 rows: one float4 per lane per row, coalesced 1KB
    int nodeBase = blockIdx.x * 32 + wave * 8;
#pragma unroll
    for (int r = 0; r < 8; ++r) {
        float4 v = ((const float4*)(h + (size_t)(nodeBase + r) * D_FEAT))[lane];
        *((float4*)&rows[(wave * 8 + r) * ROWSTRIDE + lane * 4]) = v;
    }
    __syncthreads();

    // W chain-slice into registers: wreg[i] = W[i*8 + l] (8-way LDS broadcast, free)
    float wreg[32];
#pragma unroll
    for (int i = 0; i < 32; ++i) wreg[i] = wl[i * 8 + l];

    // serial chain: acc = sum_{i} h[node][i*8+l] * W[i*8+l], strict fmaf order
    const float* myrow = &rows[(wave * 8 + g) * ROWSTRIDE];
    float acc = 0.0f;
#pragma unroll
    for (int i = 0; i < 32; ++i)
        acc = fmaf(myrow[i * 8 + l], wreg[i], acc);

    // vhaddps-style adjacent-pairwise merge tree (lane 8g+0 holds node g's z)
    float b01 = acc + __shfl_xor(acc, 1, 64);
    float b23 = b01 + __shfl_xor(b01, 2, 64);
    float z   = b23 + __shfl_xor(b23, 4, 64);

    z = z + bvec[0];
    float t = np_expf(-z);
    float s = 1.0f / (1.0f + t);       // IEEE f32 divide

    if (l == 0) {
        int node = nodeBase + g;
        __builtin_nontemporal_store(s, &s32[node]);   // re-read once, much later
        atomicAdd(&hist[bucket_of(s)], 1);
    }
}

// Parallel chunk scan: 16 blocks x 256 threads, 4 consecutive bins per thread
// (int4 coalesced). Chunk-LOCAL exclusive offsets into offs+cursor, chunk total
// into chunkSum. Global base recomputed in-register by consumer blocks (free).
__global__ void scan_chunks_kernel(const int* __restrict__ hist,
                                   int* __restrict__ offs,
                                   int* __restrict__ cursor,
                                   int* __restrict__ chunkSum) {
    __shared__ int wsum[4];
    int tid  = threadIdx.x;
    int lane = tid & 63;
    int wid  = tid >> 6;
    int base = blockIdx.x * 1024 + tid * 4;

    int4 hv = *((const int4*)(hist + base));
    int e1 = hv.x;
    int e2 = hv.x + hv.y;
    int e3 = e2 + hv.z;
    int tot = e3 + hv.w;

    int incl = tot;
#pragma unroll
    for (int d = 1; d < 64; d <<= 1) {
        int t = __shfl_up(incl, d, 64);
        if (lane >= d) incl += t;
    }
    if (lane == 63) wsum[wid] = incl;
    __syncthreads();
    int wbase = 0;
#pragma unroll
    for (int w = 0; w < 3; ++w)
        if (w < wid) wbase += wsum[w];

    int excl = wbase + (incl - tot);
    int4 ov = make_int4(excl, excl + e1, excl + e2, excl + e3);
    *((int4*)(offs + base))   = ov;
    *((int4*)(cursor + base)) = ov;
    if (tid == 255) chunkSum[blockIdx.x] = excl + tot;
}

// lanes 0..15: exclusive scan of the 16 chunk totals -> sbase (LDS)
__device__ __forceinline__ void build_base(const int* __restrict__ chunkSum,
                                           int* sbase, int tid) {
    if (tid < NCHUNK) {
        int v = chunkSum[tid];
        int inc = v;
#pragma unroll
        for (int d = 1; d < NCHUNK; d <<= 1) {
            int t = __shfl_up(inc, d, 64);
            if (tid >= d) inc += t;
        }
        sbase[tid] = inc - v;
    }
}

// Scatter + sure-member marking.
//  - Buckets whose global END <= CUTPOS are never read downstream: skip the
//    cursor atomic AND the key write entirely (~half the scatter work).
//  - Buckets whose global START >= CUTPOS are fully inside the top-k: mark
//    member bit now (removes the emit->edge ordering dependency).
__global__ void scatter_kernel(const float* __restrict__ s32,
                               int* __restrict__ cursor,
                               const int* __restrict__ offs,
                               const int* __restrict__ chunkSum,
                               unsigned int* __restrict__ bits,
                               unsigned long long* __restrict__ sk) {
    __shared__ int sbase[NCHUNK];
    int tid = threadIdx.x;
    build_base(chunkSum, sbase, tid);
    __syncthreads();
    int i = blockIdx.x * 256 + tid;
    if (i >= N_NODES) return;
    float s = s32[i];
    int b = bucket_of(s);
    int bn = b + 1;
    int gend = (bn == NBINS) ? N_NODES : sbase[bn >> 10] + offs[bn];
    if (gend <= CUTPOS) return;               // fully below cut: never read
    int pos = atomicAdd(&cursor[b], 1);       // chunk-local position
    int gbase = sbase[b >> 10];
    unsigned long long key =
        ((unsigned long long)__float_as_uint(s) << 32) | (unsigned)(~i);
    sk[gbase + pos] = key;
    if (gbase + offs[b] >= CUTPOS)            // fully above cut: sure member
        atomicOr(&bits[(unsigned)i >> 5], 1u << (i & 31));
}

// One thread per bucket; insertion sort ascending by u64 key == (s asc,
// id desc); reversed (descending) read order == lax.top_k tie rule.
// Buckets entirely below the cut are never read -> skip. The (single)
// boundary bucket marks its suffix's member bits after sorting.
__global__ void bucket_sort_kernel(const int* __restrict__ offs,
                                   const int* __restrict__ chunkSum,
                                   unsigned int* __restrict__ bits,
                                   unsigned long long* __restrict__ sk) {
    __shared__ int sbase[NCHUNK];
    int tid = threadIdx.x;
    build_base(chunkSum, sbase, tid);
    __syncthreads();
    int b = blockIdx.x * 256 + tid;
    int s0 = sbase[b >> 10] + offs[b];
    int e  = (b == NBINS - 1) ? N_NODES : sbase[(b + 1) >> 10] + offs[b + 1];
    if (e <= CUTPOS) return;
    for (int i = s0 + 1; i < e; ++i) {
        unsigned long long k = sk[i];
        int j = i - 1;
        while (j >= s0) {
            unsigned long long pk = sk[j];
            if (pk <= k) break;
            sk[j + 1] = pk;
            --j;
        }
        sk[j + 1] = k;
    }
    if (s0 < CUTPOS) {                        // boundary bucket: mark suffix
        for (int i = CUTPOS; i < e; ++i) {
            int id = (int)~(unsigned)sk[i];
            atomicOr(&bits[(unsigned)id >> 5], 1u << (id & 31));
        }
    }
}

__device__ __forceinline__ unsigned mem_bit(const unsigned int* __restrict__ bits,
                                            int s) {
    return (bits[(unsigned)s >> 5] >> (s & 31)) & 1u;
}

// Fused emit||edge (static split — R5's atomic queue serialized per-chunk and
// regressed 100us; independent grid-stride iterations let the HW pipeline).
// Outputs use nontemporal stores: never re-read, and skipping write-allocate
// preserves the L3-resident h/ei working set (R5 counter evidence: tail
// FETCH=38MB of 154MB reads). Inputs deliberately NOT nontemporal-loaded —
// NT loads are last-use hints and would evict that residency.
__global__ void emit_edge_kernel(const float* __restrict__ h,
                                 const unsigned long long* __restrict__ sk,
                                 const int* __restrict__ ei,
                                 const unsigned int* __restrict__ bits,
                                 float* __restrict__ out_newh,
                                 float* __restrict__ out_ids,
                                 float* __restrict__ out_mask,
                                 int E) {
    int tid = threadIdx.x;
    int bid = blockIdx.x;

    if (bid < EMIT_BLOCKS) {
        int lane = tid & 63;
        int wg   = bid * 4 + (tid >> 6);
        for (int row = wg; row < TOP_K; row += EMIT_BLOCKS * 4) {
            int p = N_NODES - 1 - row;
            unsigned long long key = sk[p];   // wave-uniform -> broadcast
            int id  = (int)~(unsigned)key;
            float s = __uint_as_float((unsigned)(key >> 32));
            if (lane == 0) __builtin_nontemporal_store((float)id, &out_ids[row]);
            const float4* hv = (const float4*)(h + (size_t)id * D_FEAT);
            float4 v = hv[lane];
            fx4 o = { v.x * s, v.y * s, v.z * s, v.w * s };
            __builtin_nontemporal_store(
                o, (fx4*)(out_newh + (size_t)row * D_FEAT) + lane);
        }
        return;
    }

    // ---- edge partition ----
    __shared__ int sflag;
    if (tid < 64) {                           // int64-vs-int32 storage detect
        int v = ei[2 * tid + 1];
        unsigned long long m = __ballot(v == 0);
        if (tid == 0) sflag = (m == ~0ULL) ? 1 : 0;
    }
    __syncthreads();
    int flag = sflag;

    int npairs = (E + 1) / 2;
    int stride = (FUSE_GRID - EMIT_BLOCKS) * 256;
    for (int k = (bid - EMIT_BLOCKS) * 256 + tid; k < npairs; k += stride) {
        int i0 = 2 * k;
        int i1 = i0 + 1;
        if (i1 < E) {
            int s0, d0, s1, d1;
            if (flag) {                    // int64 storage: value in even dword
                int4 a  = ((const int4*)ei)[k];
                int4 bq = ((const int4*)(ei + 2 * (size_t)E))[k];
                s0 = a.x;  s1 = a.z;
                d0 = bq.x; d1 = bq.z;
            } else {                       // int32 storage
                int2 a  = ((const int2*)ei)[k];
                int2 bq = ((const int2*)(ei + (size_t)E))[k];
                s0 = a.x;  s1 = a.y;
                d0 = bq.x; d1 = bq.y;
            }
            bool ok0 = ((unsigned)s0 < (unsigned)N_NODES) &&
                       ((unsigned)d0 < (unsigned)N_NODES) &&
                       mem_bit(bits, s0) && mem_bit(bits, d0);
            bool ok1 = ((unsigned)s1 < (unsigned)N_NODES) &&
                       ((unsigned)d1 < (unsigned)N_NODES) &&
                       mem_bit(bits, s1) && mem_bit(bits, d1);
            fx2 m = { ok0 ? 1.0f : 0.0f, ok1 ? 1.0f : 0.0f };
            __builtin_nontemporal_store(m, (fx2*)out_mask + k);
        } else {                           // odd-E tail (not hit for E=3.2M)
            int s0, d0;
            if (flag) { s0 = ei[2 * i0]; d0 = ei[2 * ((size_t)E + i0)]; }
            else      { s0 = ei[i0];     d0 = ei[(size_t)E + i0]; }
            bool ok0 = ((unsigned)s0 < (unsigned)N_NODES) &&
                       ((unsigned)d0 < (unsigned)N_NODES) &&
                       mem_bit(bits, s0) && mem_bit(bits, d0);
            __builtin_nontemporal_store(ok0 ? 1.0f : 0.0f, &out_mask[i0]);
        }
    }
}

extern "C" void kernel_launch(void* const* d_in, const int* in_sizes, int n_in,
                              void* d_out, int out_size, void* d_ws, size_t ws_size,
                              hipStream_t stream) {
    const float* h  = (const float*)d_in[0];
    const float* W  = (const float*)d_in[1];
    const float* bv = (const float*)d_in[2];
    const int*   ei = (const int*)d_in[3];
    const int E = in_sizes[3] / 2;

    char* ws = (char*)d_ws;
    float*              s32      = (float*)(ws + 0);
    unsigned long long* sk       = (unsigned long long*)(ws + 400000);
    int*                hist     = (int*)(ws + 1200000);
    unsigned int*       bits     = (unsigned int*)(ws + 1265536);
    int*                offs     = (int*)(ws + 1278336);
    int*                cursor   = (int*)(ws + 1343872);
    int*                chunkSum = (int*)(ws + 1409408);

    float* out      = (float*)d_out;
    float* out_newh = out;                                  // TOP_K * D_FEAT
    float* out_ids  = out + (size_t)TOP_K * D_FEAT;         // TOP_K
    float* out_mask = out + (size_t)TOP_K * D_FEAT + TOP_K; // E

    (void)hipMemsetAsync(ws + 1200000, 0, 78336, stream);   // hist + bits

    score_kernel<<<N_NODES / 32, 256, 0, stream>>>(h, W, bv, s32, hist);
    scan_chunks_kernel<<<NCHUNK, 256, 0, stream>>>(hist, offs, cursor, chunkSum);
    scatter_kernel<<<(N_NODES + 255) / 256, 256, 0, stream>>>(s32, cursor, offs,
                                                              chunkSum, bits, sk);
    bucket_sort_kernel<<<NBINS / 256, 256, 0, stream>>>(offs, chunkSum, bits, sk);
    emit_edge_kernel<<<FUSE_GRID, 256, 0, stream>>>(h, sk, ei, bits,
                                                    out_newh, out_ids, out_mask, E);
}

// Round 10
// 235.373 us; speedup vs baseline: 1.1141x; 1.1141x over previous
//
#include <hip/hip_runtime.h>
#include <math.h>

#define N_NODES 100000
#define D_FEAT  256
#define TOP_K   50000
#define NBINS   65536       // 1 thread/bucket sort: 65536 thr = 4 waves/CU (TLP!)
                            // R9 lesson: 16384 bins -> 1 wave/CU, latency cliff
#define NCHUNK  64          // NBINS / 1024 chunks for the parallel scan
#define CUTPOS  (N_NODES - TOP_K)
#define ROWSTRIDE 260       // 256 + 4 pad: bank = (4g + l + 8i) % 32 -> 2-way = free
#define NBITW   3200        // member bitmask words (ceil(100000/32)=3125, padded)
#define FUSE_GRID   2048    // emit||edge fused kernel (8 blocks/CU co-resident)
#define EMIT_BLOCKS 1408    // split ~ NT-write-dominated emit vs L3-read edge

// clang native vectors: __builtin_nontemporal_store requires these (not the
// HIP_vector_type structs float4/float2).
typedef float  fx4 __attribute__((ext_vector_type(4)));
typedef float  fx2 __attribute__((ext_vector_type(2)));

// Sort key: (float bits of s << 32) | ~id.  s = sigmoid >= 0, so IEEE bit
// order == numeric order; ascending u64 == (s asc, id desc) — reversed read
// gives (s desc, id asc) = lax.top_k tie rule.  One cacheline per element in
// the random scatter (vs two for separate ss/si), one dependent load in emit.
//
// Workspace layout (byte offsets, all 8/16B-aligned):
//         0 : s32      float[N_NODES]   (400,000)
//   400,000 : sk       u64[N_NODES]     (800,000)  bucket-sorted keys
// 1,200,000 : hist     int[NBINS]       (262,144)  } contiguous zero region
// 1,462,144 : bits     uint[NBITW]      ( 12,800)  } (274,944 B memset)
// 1,474,944 : offs     int[NBINS]       (262,144)  chunk-LOCAL exclusive offsets
// 1,737,088 : cursor   int[NBINS]       (262,144)
// 1,999,232 : chunkSum int[NCHUNK]      (256)

__device__ __forceinline__ int bucket_of(float s) {
    int b = (int)(s * 65536.0f);
    return min(max(b, 0), NBINS - 1);
}

// numpy SIMD float32 exp (FMA universal-intrinsics path) — bit-exact, verified R6.
__device__ __forceinline__ float np_expf(float x) {
    float q  = rintf(x * 1.44269504088896341f);
    float xr = fmaf(-q, 0.693359375f, x);
    xr       = fmaf(-q, -2.12194440e-4f, xr);
    float x2 = xr * xr;
    float p  = 1.9875691500E-4f;
    p = fmaf(p, xr, 1.3981999507E-3f);
    p = fmaf(p, xr, 8.3334519073E-3f);
    p = fmaf(p, xr, 4.1665795894E-2f);
    p = fmaf(p, xr, 1.6666665459E-1f);
    p = fmaf(p, xr, 5.0000001201E-1f);
    p = fmaf(p, x2, xr);
    p = p + 1.0f;
    return ldexpf(p, (int)q);
}

// OpenBLAS sgemv_t emulation, parallelized 8 lanes/node (bit-exact numerics):
// lane 8g+l runs chain l (k = i*8+l, i=0..31, serial fmaf) for node g of its wave;
// merge via shfl_xor 1,2,4 reproduces ((a0+a1)+(a2+a3))+((a4+a5)+(a6+a7)).
// Block = 256 thr = 4 waves = 32 nodes; rows staged to LDS coalesced.
// DO NOT TOUCH the numerics: bit-exact scores gate the top-k tie boundary.
__global__ void score_kernel(const float* __restrict__ h,
                             const float* __restrict__ W,
                             const float* __restrict__ bvec,
                             float* __restrict__ s32,
                             int* __restrict__ hist) {
    __shared__ float rows[32 * ROWSTRIDE];   // 33,280 B
    __shared__ float wl[256];
    int tid  = threadIdx.x;
    int wave = tid >> 6;
    int lane = tid & 63;
    int g    = lane >> 3;    // node within wave's 8
    int l    = lane & 7;     // chain id

    wl[tid] = W[tid];

    // stage this wave's 8 rows: one float4 per lane per row, coalesced 1KB
    int nodeBase = blockIdx.x * 32 + wave * 8;
#pragma unroll
    for (int r = 0; r < 8; ++r) {
        float4 v = ((const float4*)(h + (size_t)(nodeBase + r) * D_FEAT))[lane];
        *((float4*)&rows[(wave * 8 + r) * ROWSTRIDE + lane * 4]) = v;
    }
    __syncthreads();

    // W chain-slice into registers: wreg[i] = W[i*8 + l] (8-way LDS broadcast, free)
    float wreg[32];
#pragma unroll
    for (int i = 0; i < 32; ++i) wreg[i] = wl[i * 8 + l];

    // serial chain: acc = sum_{i} h[node][i*8+l] * W[i*8+l], strict fmaf order
    const float* myrow = &rows[(wave * 8 + g) * ROWSTRIDE];
    float acc = 0.0f;
#pragma unroll
    for (int i = 0; i < 32; ++i)
        acc = fmaf(myrow[i * 8 + l], wreg[i], acc);

    // vhaddps-style adjacent-pairwise merge tree (lane 8g+0 holds node g's z)
    float b01 = acc + __shfl_xor(acc, 1, 64);
    float b23 = b01 + __shfl_xor(b01, 2, 64);
    float z   = b23 + __shfl_xor(b23, 4, 64);

    z = z + bvec[0];
    float t = np_expf(-z);
    float s = 1.0f / (1.0f + t);       // IEEE f32 divide

    if (l == 0) {
        int node = nodeBase + g;
        __builtin_nontemporal_store(s, &s32[node]);   // re-read once, much later
        atomicAdd(&hist[bucket_of(s)], 1);
    }
}

// Parallel chunk scan: 64 blocks x 256 threads, 4 consecutive bins per thread
// (int4 coalesced). Chunk-LOCAL exclusive offsets into offs+cursor, chunk total
// into chunkSum. Global base recomputed in-register by consumer blocks (free).
__global__ void scan_chunks_kernel(const int* __restrict__ hist,
                                   int* __restrict__ offs,
                                   int* __restrict__ cursor,
                                   int* __restrict__ chunkSum) {
    __shared__ int wsum[4];
    int tid  = threadIdx.x;
    int lane = tid & 63;
    int wid  = tid >> 6;
    int base = blockIdx.x * 1024 + tid * 4;

    int4 hv = *((const int4*)(hist + base));
    int e1 = hv.x;
    int e2 = hv.x + hv.y;
    int e3 = e2 + hv.z;
    int tot = e3 + hv.w;

    int incl = tot;
#pragma unroll
    for (int d = 1; d < 64; d <<= 1) {
        int t = __shfl_up(incl, d, 64);
        if (lane >= d) incl += t;
    }
    if (lane == 63) wsum[wid] = incl;
    __syncthreads();
    int wbase = 0;
#pragma unroll
    for (int w = 0; w < 3; ++w)
        if (w < wid) wbase += wsum[w];

    int excl = wbase + (incl - tot);
    int4 ov = make_int4(excl, excl + e1, excl + e2, excl + e3);
    *((int4*)(offs + base))   = ov;
    *((int4*)(cursor + base)) = ov;
    if (tid == 255) chunkSum[blockIdx.x] = excl + tot;
}

// wave-0: exclusive scan of the 64 chunk totals -> sbase (LDS)
__device__ __forceinline__ void build_base(const int* __restrict__ chunkSum,
                                           int* sbase, int tid) {
    if (tid < NCHUNK) {
        int v = chunkSum[tid];
        int inc = v;
#pragma unroll
        for (int d = 1; d < NCHUNK; d <<= 1) {
            int t = __shfl_up(inc, d, 64);
            if (tid >= d) inc += t;
        }
        sbase[tid] = inc - v;
    }
}

// Scatter + sure-member marking.
//  - Buckets whose global END <= CUTPOS are never read downstream: skip the
//    cursor atomic AND the key write entirely (~half the scatter work).
//  - Buckets whose global START >= CUTPOS are fully inside the top-k: mark
//    member bit now (removes the emit->edge ordering dependency).
__global__ void scatter_kernel(const float* __restrict__ s32,
                               int* __restrict__ cursor,
                               const int* __restrict__ offs,
                               const int* __restrict__ chunkSum,
                               unsigned int* __restrict__ bits,
                               unsigned long long* __restrict__ sk) {
    __shared__ int sbase[NCHUNK];
    int tid = threadIdx.x;
    build_base(chunkSum, sbase, tid);
    __syncthreads();
    int i = blockIdx.x * 256 + tid;
    if (i >= N_NODES) return;
    float s = s32[i];
    int b = bucket_of(s);
    int bn = b + 1;
    int gend = (bn == NBINS) ? N_NODES : sbase[bn >> 10] + offs[bn];
    if (gend <= CUTPOS) return;               // fully below cut: never read
    int pos = atomicAdd(&cursor[b], 1);       // chunk-local position
    int gbase = sbase[b >> 10];
    unsigned long long key =
        ((unsigned long long)__float_as_uint(s) << 32) | (unsigned)(~i);
    sk[gbase + pos] = key;
    if (gbase + offs[b] >= CUTPOS)            // fully above cut: sure member
        atomicOr(&bits[(unsigned)i >> 5], 1u << (i & 31));
}

// One thread per bucket; insertion sort ascending by u64 key == (s asc,
// id desc); reversed (descending) read order == lax.top_k tie rule.
// Buckets entirely below the cut are never read -> skip. The (single)
// boundary bucket marks its suffix's member bits after sorting.
__global__ void bucket_sort_kernel(const int* __restrict__ offs,
                                   const int* __restrict__ chunkSum,
                                   unsigned int* __restrict__ bits,
                                   unsigned long long* __restrict__ sk) {
    __shared__ int sbase[NCHUNK];
    int tid = threadIdx.x;
    build_base(chunkSum, sbase, tid);
    __syncthreads();
    int b = blockIdx.x * 256 + tid;
    int s0 = sbase[b >> 10] + offs[b];
    int e  = (b == NBINS - 1) ? N_NODES : sbase[(b + 1) >> 10] + offs[b + 1];
    if (e <= CUTPOS) return;
    for (int i = s0 + 1; i < e; ++i) {
        unsigned long long k = sk[i];
        int j = i - 1;
        while (j >= s0) {
            unsigned long long pk = sk[j];
            if (pk <= k) break;
            sk[j + 1] = pk;
            --j;
        }
        sk[j + 1] = k;
    }
    if (s0 < CUTPOS) {                        // boundary bucket: mark suffix
        for (int i = CUTPOS; i < e; ++i) {
            int id = (int)~(unsigned)sk[i];
            atomicOr(&bits[(unsigned)id >> 5], 1u << (id & 31));
        }
    }
}

__device__ __forceinline__ unsigned mem_bit(const unsigned int* __restrict__ bits,
                                            int s) {
    return (bits[(unsigned)s >> 5] >> (s & 31)) & 1u;
}

// Fused emit||edge (static split — R5's atomic queue serialized per-chunk and
// regressed 100us; independent grid-stride iterations let the HW pipeline).
// Outputs use nontemporal stores: never re-read, and skipping write-allocate
// preserves the L3-resident h/ei working set (R5 counter evidence: tail
// FETCH=38MB of 154MB reads). Inputs deliberately NOT nontemporal-loaded —
// NT loads are last-use hints and would evict that residency.
__global__ void emit_edge_kernel(const float* __restrict__ h,
                                 const unsigned long long* __restrict__ sk,
                                 const int* __restrict__ ei,
                                 const unsigned int* __restrict__ bits,
                                 float* __restrict__ out_newh,
                                 float* __restrict__ out_ids,
                                 float* __restrict__ out_mask,
                                 int E) {
    int tid = threadIdx.x;
    int bid = blockIdx.x;

    if (bid < EMIT_BLOCKS) {
        int lane = tid & 63;
        int wg   = bid * 4 + (tid >> 6);
        for (int row = wg; row < TOP_K; row += EMIT_BLOCKS * 4) {
            int p = N_NODES - 1 - row;
            unsigned long long key = sk[p];   // wave-uniform -> broadcast
            int id  = (int)~(unsigned)key;
            float s = __uint_as_float((unsigned)(key >> 32));
            if (lane == 0) __builtin_nontemporal_store((float)id, &out_ids[row]);
            const float4* hv = (const float4*)(h + (size_t)id * D_FEAT);
            float4 v = hv[lane];
            fx4 o = { v.x * s, v.y * s, v.z * s, v.w * s };
            __builtin_nontemporal_store(
                o, (fx4*)(out_newh + (size_t)row * D_FEAT) + lane);
        }
        return;
    }

    // ---- edge partition ----
    __shared__ int sflag;
    if (tid < 64) {                           // int64-vs-int32 storage detect
        int v = ei[2 * tid + 1];
        unsigned long long m = __ballot(v == 0);
        if (tid == 0) sflag = (m == ~0ULL) ? 1 : 0;
    }
    __syncthreads();
    int flag = sflag;

    int npairs = (E + 1) / 2;
    int stride = (FUSE_GRID - EMIT_BLOCKS) * 256;
    for (int k = (bid - EMIT_BLOCKS) * 256 + tid; k < npairs; k += stride) {
        int i0 = 2 * k;
        int i1 = i0 + 1;
        if (i1 < E) {
            int s0, d0, s1, d1;
            if (flag) {                    // int64 storage: value in even dword
                int4 a  = ((const int4*)ei)[k];
                int4 bq = ((const int4*)(ei + 2 * (size_t)E))[k];
                s0 = a.x;  s1 = a.z;
                d0 = bq.x; d1 = bq.z;
            } else {                       // int32 storage
                int2 a  = ((const int2*)ei)[k];
                int2 bq = ((const int2*)(ei + (size_t)E))[k];
                s0 = a.x;  s1 = a.y;
                d0 = bq.x; d1 = bq.y;
            }
            bool ok0 = ((unsigned)s0 < (unsigned)N_NODES) &&
                       ((unsigned)d0 < (unsigned)N_NODES) &&
                       mem_bit(bits, s0) && mem_bit(bits, d0);
            bool ok1 = ((unsigned)s1 < (unsigned)N_NODES) &&
                       ((unsigned)d1 < (unsigned)N_NODES) &&
                       mem_bit(bits, s1) && mem_bit(bits, d1);
            fx2 m = { ok0 ? 1.0f : 0.0f, ok1 ? 1.0f : 0.0f };
            __builtin_nontemporal_store(m, (fx2*)out_mask + k);
        } else {                           // odd-E tail (not hit for E=3.2M)
            int s0, d0;
            if (flag) { s0 = ei[2 * i0]; d0 = ei[2 * ((size_t)E + i0)]; }
            else      { s0 = ei[i0];     d0 = ei[(size_t)E + i0]; }
            bool ok0 = ((unsigned)s0 < (unsigned)N_NODES) &&
                       ((unsigned)d0 < (unsigned)N_NODES) &&
                       mem_bit(bits, s0) && mem_bit(bits, d0);
            __builtin_nontemporal_store(ok0 ? 1.0f : 0.0f, &out_mask[i0]);
        }
    }
}

extern "C" void kernel_launch(void* const* d_in, const int* in_sizes, int n_in,
                              void* d_out, int out_size, void* d_ws, size_t ws_size,
                              hipStream_t stream) {
    const float* h  = (const float*)d_in[0];
    const float* W  = (const float*)d_in[1];
    const float* bv = (const float*)d_in[2];
    const int*   ei = (const int*)d_in[3];
    const int E = in_sizes[3] / 2;

    char* ws = (char*)d_ws;
    float*              s32      = (float*)(ws + 0);
    unsigned long long* sk       = (unsigned long long*)(ws + 400000);
    int*                hist     = (int*)(ws + 1200000);
    unsigned int*       bits     = (unsigned int*)(ws + 1462144);
    int*                offs     = (int*)(ws + 1474944);
    int*                cursor   = (int*)(ws + 1737088);
    int*                chunkSum = (int*)(ws + 1999232);

    float* out      = (float*)d_out;
    float* out_newh = out;                                  // TOP_K * D_FEAT
    float* out_ids  = out + (size_t)TOP_K * D_FEAT;         // TOP_K
    float* out_mask = out + (size_t)TOP_K * D_FEAT + TOP_K; // E

    (void)hipMemsetAsync(ws + 1200000, 0, 274944, stream);  // hist + bits

    score_kernel<<<N_NODES / 32, 256, 0, stream>>>(h, W, bv, s32, hist);
    scan_chunks_kernel<<<NCHUNK, 256, 0, stream>>>(hist, offs, cursor, chunkSum);
    scatter_kernel<<<(N_NODES + 255) / 256, 256, 0, stream>>>(s32, cursor, offs,
                                                              chunkSum, bits, sk);
    bucket_sort_kernel<<<NBINS / 256, 256, 0, stream>>>(offs, chunkSum, bits, sk);
    emit_edge_kernel<<<FUSE_GRID, 256, 0, stream>>>(h, sk, ei, bits,
                                                    out_newh, out_ids, out_mask, E);
}